// Round 5
// baseline (110.587 us; speedup 1.0000x reference)
//
#include <hip/hip_runtime.h>

static constexpr int N = 100000;
static constexpr int E = 3200000;
static constexpr int BUKSHIFT = 8;
static constexpr int BUKSZ = 1 << BUKSHIFT;             // 256 nodes / bucket
static constexpr int BUKMASK = BUKSZ - 1;
static constexpr int NBUK = (N + BUKSZ - 1) / BUKSZ;    // 391
static constexpr int CAP = 12288;                        // slots per bucket region
static constexpr int SC_CHUNK = 16384;
static constexpr int SC_T = 1024;
static constexpr int SC_BLOCKS = (E + SC_CHUNK - 1) / SC_CHUNK;  // 196

// ws (4B elems): binned[NBUK*CAP] | dinv[N] | y1[N] | m[N] | gofs[NBUK] | partials[NBUK*16]

__global__ void k_init(int* __restrict__ gofs) {
    int i = threadIdx.x;
    if (i < NBUK) gofs[i] = i * CAP;
}

// Block-local counting sort of 16384 edges by destination bucket, then
// bucket-contiguous (coalesced-run) writes into fixed-capacity regions.
__global__ __launch_bounds__(SC_T) void k_scatter(const int4* __restrict__ rows4,
                                                  const int4* __restrict__ cols4,
                                                  int* __restrict__ gofs,
                                                  int* __restrict__ binned) {
    __shared__ int hist[4][NBUK];   // replica hists -> replica-exclusive bases
    __shared__ int cnt[512];        // padded, scanned inclusive
    __shared__ int lbase[NBUK];
    __shared__ int gbase[NBUK];
    __shared__ int stag[SC_CHUNK];

    const int tid = threadIdx.x;
    const int g = tid >> 8;         // 4 replica groups
    for (int i = tid; i < 4 * NBUK; i += SC_T) (&hist[0][0])[i] = 0;
    if (tid < 512) cnt[tid] = 0;
    __syncthreads();

    const int nI4 = E / 4;
    const int base4 = blockIdx.x * (SC_CHUNK / 4);
    int4 r[4], c[4];
    bool vld[4];
    #pragma unroll
    for (int k = 0; k < 4; ++k) {
        int idx = base4 + k * SC_T + tid;
        vld[k] = idx < nI4;
        if (vld[k]) { r[k] = rows4[idx]; c[k] = cols4[idx]; }
    }
    #pragma unroll
    for (int k = 0; k < 4; ++k) if (vld[k]) {
        atomicAdd(&hist[g][c[k].x >> BUKSHIFT], 1);
        atomicAdd(&hist[g][c[k].y >> BUKSHIFT], 1);
        atomicAdd(&hist[g][c[k].z >> BUKSHIFT], 1);
        atomicAdd(&hist[g][c[k].w >> BUKSHIFT], 1);
    }
    __syncthreads();

    if (tid < NBUK) {
        int h0 = hist[0][tid], h1 = hist[1][tid], h2 = hist[2][tid], h3 = hist[3][tid];
        hist[0][tid] = 0; hist[1][tid] = h0; hist[2][tid] = h0 + h1; hist[3][tid] = h0 + h1 + h2;
        int cc = h0 + h1 + h2 + h3;
        cnt[tid] = cc;
        gbase[tid] = cc ? atomicAdd(&gofs[tid], cc) : 0;
    }
    __syncthreads();
    for (int off = 1; off < 512; off <<= 1) {
        int v = 0;
        if (tid < 512) { v = cnt[tid]; if (tid >= off) v += cnt[tid - off]; }
        __syncthreads();
        if (tid < 512) cnt[tid] = v;
        __syncthreads();
    }
    if (tid < NBUK) lbase[tid] = tid ? cnt[tid - 1] : 0;
    __syncthreads();

    #pragma unroll
    for (int k = 0; k < 4; ++k) if (vld[k]) {
        int b, off;
        b = c[k].x >> BUKSHIFT; off = atomicAdd(&hist[g][b], 1); stag[lbase[b] + off] = (r[k].x << BUKSHIFT) | (c[k].x & BUKMASK);
        b = c[k].y >> BUKSHIFT; off = atomicAdd(&hist[g][b], 1); stag[lbase[b] + off] = (r[k].y << BUKSHIFT) | (c[k].y & BUKMASK);
        b = c[k].z >> BUKSHIFT; off = atomicAdd(&hist[g][b], 1); stag[lbase[b] + off] = (r[k].z << BUKSHIFT) | (c[k].z & BUKMASK);
        b = c[k].w >> BUKSHIFT; off = atomicAdd(&hist[g][b], 1); stag[lbase[b] + off] = (r[k].w << BUKSHIFT) | (c[k].w & BUKMASK);
    }
    __syncthreads();

    const int eTot = min(SC_CHUNK, E - blockIdx.x * SC_CHUNK);
    int s = tid * 16;
    if (s < eTot) {
        int lo = 0, hi = NBUK - 1;
        while (lo < hi) { int mid = (lo + hi + 1) >> 1; if (lbase[mid] <= s) lo = mid; else hi = mid - 1; }
        int b = lo;
        const int e1 = min(s + 16, eTot);
        for (; s < e1; ++s) {
            while (b + 1 < NBUK && lbase[b + 1] <= s) ++b;
            binned[gbase[b] + (s - lbase[b])] = stag[s];
        }
    }
}

// per-bucket degree -> dinv, y1
__global__ __launch_bounds__(1024) void k_deg(const int* __restrict__ binned,
                                              const int* __restrict__ gofs,
                                              const float* __restrict__ x,
                                              float* __restrict__ dinv,
                                              float* __restrict__ y1) {
    __shared__ int cnt[8][BUKSZ];
    const int tid = threadIdx.x;
    for (int i = tid; i < 8 * BUKSZ; i += 1024) (&cnt[0][0])[i] = 0;
    __syncthreads();
    const int b = blockIdx.x, g = tid >> 7;
    const int s0 = b * CAP;
    const int n = gofs[b] - s0;
    const int n4 = n >> 2;
    const int4* b4 = (const int4*)(binned + s0);
    for (int i = tid; i < n4; i += 1024) {
        int4 p = b4[i];
        atomicAdd(&cnt[g][p.x & BUKMASK], 1);
        atomicAdd(&cnt[g][p.y & BUKMASK], 1);
        atomicAdd(&cnt[g][p.z & BUKMASK], 1);
        atomicAdd(&cnt[g][p.w & BUKMASK], 1);
    }
    if (tid < (n & 3)) atomicAdd(&cnt[g][binned[s0 + (n4 << 2) + tid] & BUKMASK], 1);
    __syncthreads();
    if (tid < BUKSZ) {
        int v = (b << BUKSHIFT) + tid;
        if (v < N) {
            int c = 0;
            #pragma unroll
            for (int q = 0; q < 8; ++q) c += cnt[q][tid];
            float d = rsqrtf(1.0f + (float)c);
            dinv[v] = d;
            y1[v] = d * x[v];
        }
    }
}

// per-bucket acc1 -> m
__global__ __launch_bounds__(1024) void k_acc1(const int* __restrict__ binned,
                                               const int* __restrict__ gofs,
                                               const float* __restrict__ y1,
                                               const float* __restrict__ dinv,
                                               float* __restrict__ m) {
    __shared__ float acc[8][BUKSZ];
    const int tid = threadIdx.x;
    for (int i = tid; i < 8 * BUKSZ; i += 1024) (&acc[0][0])[i] = 0.f;
    __syncthreads();
    const int b = blockIdx.x, g = tid >> 7;
    const int s0 = b * CAP;
    const int n = gofs[b] - s0;
    const int n4 = n >> 2;
    const int4* b4 = (const int4*)(binned + s0);
    for (int i = tid; i < n4; i += 1024) {
        int4 p = b4[i];
        atomicAdd(&acc[g][p.x & BUKMASK], y1[p.x >> BUKSHIFT]);
        atomicAdd(&acc[g][p.y & BUKMASK], y1[p.y >> BUKSHIFT]);
        atomicAdd(&acc[g][p.z & BUKMASK], y1[p.z >> BUKSHIFT]);
        atomicAdd(&acc[g][p.w & BUKMASK], y1[p.w >> BUKSHIFT]);
    }
    if (tid < (n & 3)) {
        int p = binned[s0 + (n4 << 2) + tid];
        atomicAdd(&acc[g][p & BUKMASK], y1[p >> BUKSHIFT]);
    }
    __syncthreads();
    if (tid < BUKSZ) {
        int v = (b << BUKSHIFT) + tid;
        if (v < N) {
            float a = 0.f;
            #pragma unroll
            for (int q = 0; q < 8; ++q) a += acc[q][tid];
            float d = dinv[v];
            float s = d * a + d * y1[v];
            m[v] = d * s;
        }
    }
}

// per-bucket tpos/tneg -> h2 -> per-block partial column sums
__global__ __launch_bounds__(1024) void k_acc2(const int* __restrict__ binned,
                                               const int* __restrict__ gofs,
                                               const float* __restrict__ m,
                                               const float* __restrict__ dinv,
                                               const float* __restrict__ W1,
                                               const float* __restrict__ W2,
                                               float* __restrict__ partials) {
    __shared__ float tp[8][BUKSZ], tn[8][BUKSZ];
    __shared__ float sP[16], sM[16], sAcc[16];
    const int tid = threadIdx.x;
    if (tid < 16) {
        float p = 0.f, q = 0.f;
        for (int k = 0; k < 16; ++k) {
            float w1 = W1[k];
            float w2 = W2[k * 16 + tid];
            p += fmaxf(w1, 0.f) * w2;
            q += fminf(w1, 0.f) * w2;
        }
        sP[tid] = p; sM[tid] = q; sAcc[tid] = 0.f;
    }
    for (int i = tid; i < 8 * BUKSZ; i += 1024) { (&tp[0][0])[i] = 0.f; (&tn[0][0])[i] = 0.f; }
    __syncthreads();
    const int b = blockIdx.x, g = tid >> 7;
    const int s0 = b * CAP;
    const int n = gofs[b] - s0;
    const int n4 = n >> 2;
    const int4* b4 = (const int4*)(binned + s0);
    for (int i = tid; i < n4; i += 1024) {
        int4 p = b4[i];
        float v0 = m[p.x >> BUKSHIFT], v1 = m[p.y >> BUKSHIFT];
        float v2 = m[p.z >> BUKSHIFT], v3 = m[p.w >> BUKSHIFT];
        atomicAdd(v0 >= 0.f ? &tp[g][p.x & BUKMASK] : &tn[g][p.x & BUKMASK], v0);
        atomicAdd(v1 >= 0.f ? &tp[g][p.y & BUKMASK] : &tn[g][p.y & BUKMASK], v1);
        atomicAdd(v2 >= 0.f ? &tp[g][p.z & BUKMASK] : &tn[g][p.z & BUKMASK], v2);
        atomicAdd(v3 >= 0.f ? &tp[g][p.w & BUKMASK] : &tn[g][p.w & BUKMASK], v3);
    }
    if (tid < (n & 3)) {
        int p = binned[s0 + (n4 << 2) + tid];
        float val = m[p >> BUKSHIFT];
        atomicAdd(val >= 0.f ? &tp[g][p & BUKMASK] : &tn[g][p & BUKMASK], val);
    }
    __syncthreads();
    float alpha = 0.f, beta = 0.f;
    if (tid < BUKSZ) {
        int v = (b << BUKSHIFT) + tid;
        if (v < N) {
            float a = 0.f, bb = 0.f;
            #pragma unroll
            for (int q = 0; q < 8; ++q) { a += tp[q][tid]; bb += tn[q][tid]; }
            float d = dinv[v], mv = m[v];
            alpha = d * a;
            beta  = d * bb;
            float self = d * mv;
            if (mv >= 0.f) alpha += self; else beta += self;
        }
    }
    const int lane = tid & 63;
    for (int j = 0; j < 16; ++j) {
        float h = fmaxf(alpha * sP[j] + beta * sM[j], 0.f);
        #pragma unroll
        for (int off = 32; off > 0; off >>= 1) h += __shfl_down(h, off);
        if (lane == 0 && h != 0.f) atomicAdd(&sAcc[j], h);
    }
    __syncthreads();
    if (tid < 16) partials[b * 16 + tid] = sAcc[tid];
}

// reduce partials[NBUK][16] -> mean -> out = g @ W3 + b
__global__ void k_out(const float* __restrict__ partials, const float* __restrict__ W3,
                      const float* __restrict__ b, float* __restrict__ out) {
    __shared__ float s[16][16];
    int j = threadIdx.x & 15;
    int g = threadIdx.x >> 4;
    float acc = 0.f;
    for (int blk = g; blk < NBUK; blk += 16) acc += partials[blk * 16 + j];
    s[g][j] = acc;
    __syncthreads();
    if (threadIdx.x < 16) {
        float tot = 0.f;
        #pragma unroll
        for (int gg = 0; gg < 16; ++gg) tot += s[gg][threadIdx.x];
        s[0][threadIdx.x] = tot * (1.0f / (float)N);
    }
    __syncthreads();
    if (threadIdx.x < 11) {
        float acc2 = b[threadIdx.x];
        #pragma unroll
        for (int k = 0; k < 16; ++k) acc2 += s[0][k] * W3[k * 11 + threadIdx.x];
        out[threadIdx.x] = acc2;
    }
}

extern "C" void kernel_launch(void* const* d_in, const int* in_sizes, int n_in,
                              void* d_out, int out_size, void* d_ws, size_t ws_size,
                              hipStream_t stream) {
    const float* x  = (const float*)d_in[0];
    const int*   ei = (const int*)d_in[1];   // [2*E]: rows then cols (int32)
    const float* W1 = (const float*)d_in[2];
    const float* W2 = (const float*)d_in[3];
    const float* W3 = (const float*)d_in[4];
    const float* b  = (const float*)d_in[5];
    float* out = (float*)d_out;

    int*   wsi      = (int*)d_ws;
    int*   binned   = wsi;                             // NBUK*CAP
    float* dinv     = (float*)(wsi + (size_t)NBUK * CAP);
    float* y1       = dinv + N;
    float* m        = y1 + N;
    int*   gofs     = (int*)(m + N);                   // NBUK
    float* partials = (float*)(gofs + NBUK);           // NBUK*16

    const int4* rows4 = (const int4*)ei;
    const int4* cols4 = (const int4*)(ei + E);

    k_init   <<<1, 512, 0, stream>>>(gofs);
    k_scatter<<<SC_BLOCKS, SC_T, 0, stream>>>(rows4, cols4, gofs, binned);
    k_deg    <<<NBUK, 1024, 0, stream>>>(binned, gofs, x, dinv, y1);
    k_acc1   <<<NBUK, 1024, 0, stream>>>(binned, gofs, y1, dinv, m);
    k_acc2   <<<NBUK, 1024, 0, stream>>>(binned, gofs, m, dinv, W1, W2, partials);
    k_out    <<<1, 256, 0, stream>>>(partials, W3, b, out);
}

// Round 6
// 108.344 us; speedup vs baseline: 1.0207x; 1.0207x over previous
//
#include <hip/hip_runtime.h>

static constexpr int N = 100000;
static constexpr int E = 3200000;
static constexpr int BUKSHIFT = 8;
static constexpr int BUKSZ = 1 << BUKSHIFT;             // 256 nodes / bucket
static constexpr int BUKMASK = BUKSZ - 1;
static constexpr int NBUK = (N + BUKSZ - 1) / BUKSZ;    // 391
static constexpr int NGRP = 8;                           // reservation groups
static constexpr int SUBCAP = 1536;                      // slots per (bucket,group)
static constexpr int CAP = NGRP * SUBCAP;                // 12288 per bucket
static constexpr int GSTRIDE = 16;                       // pad counters to 64B lines
static constexpr int SC_CHUNK = 8192;
static constexpr int SC_T = 1024;
static constexpr int SC_BLOCKS = (E + SC_CHUNK - 1) / SC_CHUNK;  // 391

// ws (4B): binned[NBUK*CAP] | dinv[N] | y1[N] | m[N] | gofs[NBUK*NGRP*GSTRIDE] | partials[NBUK*16]

__global__ void k_init(int* __restrict__ gofs) {
    int i = blockIdx.x * blockDim.x + threadIdx.x;
    if (i < NBUK * NGRP) {
        int b = i / NGRP, g = i % NGRP;
        gofs[i * GSTRIDE] = b * CAP + g * SUBCAP;
    }
}

// Block-local counting sort of 8192 edges by destination bucket, then
// coalesced copy-out into this block's group sub-segments (padded counters).
__global__ __launch_bounds__(SC_T) void k_scatter(const int4* __restrict__ rows4,
                                                  const int4* __restrict__ cols4,
                                                  int* __restrict__ gofs,
                                                  int* __restrict__ binned) {
    __shared__ int hist[4][NBUK];   // replica hists -> replica-exclusive bases
    __shared__ int cnt[512];
    __shared__ int lbase[NBUK];
    __shared__ int gbase[NBUK];
    __shared__ int stag[SC_CHUNK];

    const int tid = threadIdx.x;
    const int g = tid >> 8;                 // 4 hist replica groups
    const int grp = blockIdx.x & (NGRP - 1);
    for (int i = tid; i < 4 * NBUK; i += SC_T) (&hist[0][0])[i] = 0;
    if (tid < 512) cnt[tid] = 0;
    __syncthreads();

    const int nI4 = E / 4;
    const int base4 = blockIdx.x * (SC_CHUNK / 4);
    const int ia = base4 + tid, ib = base4 + 1024 + tid;
    const bool va = ia < nI4, vb = ib < nI4;
    int4 ra, ca, rb, cb;
    if (va) { ra = rows4[ia]; ca = cols4[ia]; }
    if (vb) { rb = rows4[ib]; cb = cols4[ib]; }

    if (va) {
        atomicAdd(&hist[g][ca.x >> BUKSHIFT], 1);
        atomicAdd(&hist[g][ca.y >> BUKSHIFT], 1);
        atomicAdd(&hist[g][ca.z >> BUKSHIFT], 1);
        atomicAdd(&hist[g][ca.w >> BUKSHIFT], 1);
    }
    if (vb) {
        atomicAdd(&hist[g][cb.x >> BUKSHIFT], 1);
        atomicAdd(&hist[g][cb.y >> BUKSHIFT], 1);
        atomicAdd(&hist[g][cb.z >> BUKSHIFT], 1);
        atomicAdd(&hist[g][cb.w >> BUKSHIFT], 1);
    }
    __syncthreads();

    if (tid < NBUK) {
        int h0 = hist[0][tid], h1 = hist[1][tid], h2 = hist[2][tid], h3 = hist[3][tid];
        hist[0][tid] = 0; hist[1][tid] = h0; hist[2][tid] = h0 + h1; hist[3][tid] = h0 + h1 + h2;
        int c = h0 + h1 + h2 + h3;
        cnt[tid] = c;
        gbase[tid] = c ? atomicAdd(&gofs[(tid * NGRP + grp) * GSTRIDE], c) : 0;
    }
    __syncthreads();
    for (int off = 1; off < 512; off <<= 1) {
        int v = 0;
        if (tid < 512) { v = cnt[tid]; if (tid >= off) v += cnt[tid - off]; }
        __syncthreads();
        if (tid < 512) cnt[tid] = v;
        __syncthreads();
    }
    if (tid < NBUK) lbase[tid] = tid ? cnt[tid - 1] : 0;
    __syncthreads();

    if (va) {
        int b, off;
        b = ca.x >> BUKSHIFT; off = atomicAdd(&hist[g][b], 1); stag[lbase[b] + off] = (ra.x << BUKSHIFT) | (ca.x & BUKMASK);
        b = ca.y >> BUKSHIFT; off = atomicAdd(&hist[g][b], 1); stag[lbase[b] + off] = (ra.y << BUKSHIFT) | (ca.y & BUKMASK);
        b = ca.z >> BUKSHIFT; off = atomicAdd(&hist[g][b], 1); stag[lbase[b] + off] = (ra.z << BUKSHIFT) | (ca.z & BUKMASK);
        b = ca.w >> BUKSHIFT; off = atomicAdd(&hist[g][b], 1); stag[lbase[b] + off] = (ra.w << BUKSHIFT) | (ca.w & BUKMASK);
    }
    if (vb) {
        int b, off;
        b = cb.x >> BUKSHIFT; off = atomicAdd(&hist[g][b], 1); stag[lbase[b] + off] = (rb.x << BUKSHIFT) | (cb.x & BUKMASK);
        b = cb.y >> BUKSHIFT; off = atomicAdd(&hist[g][b], 1); stag[lbase[b] + off] = (rb.y << BUKSHIFT) | (cb.y & BUKMASK);
        b = cb.z >> BUKSHIFT; off = atomicAdd(&hist[g][b], 1); stag[lbase[b] + off] = (rb.z << BUKSHIFT) | (cb.z & BUKMASK);
        b = cb.w >> BUKSHIFT; off = atomicAdd(&hist[g][b], 1); stag[lbase[b] + off] = (rb.w << BUKSHIFT) | (cb.w & BUKMASK);
    }
    __syncthreads();

    const int eTot = min(SC_CHUNK, E - blockIdx.x * SC_CHUNK);
    int s = tid * 8;
    if (s < eTot) {
        int lo = 0, hi = NBUK - 1;
        while (lo < hi) { int mid = (lo + hi + 1) >> 1; if (lbase[mid] <= s) lo = mid; else hi = mid - 1; }
        int b = lo;
        const int e1 = min(s + 8, eTot);
        for (; s < e1; ++s) {
            while (b + 1 < NBUK && lbase[b + 1] <= s) ++b;
            binned[gbase[b] + (s - lbase[b])] = stag[s];
        }
    }
}

// per-bucket degree -> dinv, y1
__global__ __launch_bounds__(1024) void k_deg(const int* __restrict__ binned,
                                              const int* __restrict__ gofs,
                                              const float* __restrict__ x,
                                              float* __restrict__ dinv,
                                              float* __restrict__ y1) {
    __shared__ int cnt[8][BUKSZ];
    const int tid = threadIdx.x;
    for (int i = tid; i < 8 * BUKSZ; i += 1024) (&cnt[0][0])[i] = 0;
    __syncthreads();
    const int b = blockIdx.x, g = tid >> 7;
    for (int sg = 0; sg < NGRP; ++sg) {
        const int s0 = b * CAP + sg * SUBCAP;
        const int n = gofs[(b * NGRP + sg) * GSTRIDE] - s0;
        const int n4 = n >> 2;
        const int4* b4 = (const int4*)(binned + s0);
        for (int i = tid; i < n4; i += 1024) {
            int4 p = b4[i];
            atomicAdd(&cnt[g][p.x & BUKMASK], 1);
            atomicAdd(&cnt[g][p.y & BUKMASK], 1);
            atomicAdd(&cnt[g][p.z & BUKMASK], 1);
            atomicAdd(&cnt[g][p.w & BUKMASK], 1);
        }
        if (tid < (n & 3)) atomicAdd(&cnt[g][binned[s0 + (n4 << 2) + tid] & BUKMASK], 1);
    }
    __syncthreads();
    if (tid < BUKSZ) {
        int v = (b << BUKSHIFT) + tid;
        if (v < N) {
            int c = 0;
            #pragma unroll
            for (int q = 0; q < 8; ++q) c += cnt[q][tid];
            float d = rsqrtf(1.0f + (float)c);
            dinv[v] = d;
            y1[v] = d * x[v];
        }
    }
}

// per-bucket acc1 -> m
__global__ __launch_bounds__(1024) void k_acc1(const int* __restrict__ binned,
                                               const int* __restrict__ gofs,
                                               const float* __restrict__ y1,
                                               const float* __restrict__ dinv,
                                               float* __restrict__ m) {
    __shared__ float acc[8][BUKSZ];
    const int tid = threadIdx.x;
    for (int i = tid; i < 8 * BUKSZ; i += 1024) (&acc[0][0])[i] = 0.f;
    __syncthreads();
    const int b = blockIdx.x, g = tid >> 7;
    for (int sg = 0; sg < NGRP; ++sg) {
        const int s0 = b * CAP + sg * SUBCAP;
        const int n = gofs[(b * NGRP + sg) * GSTRIDE] - s0;
        const int n4 = n >> 2;
        const int4* b4 = (const int4*)(binned + s0);
        for (int i = tid; i < n4; i += 1024) {
            int4 p = b4[i];
            atomicAdd(&acc[g][p.x & BUKMASK], y1[p.x >> BUKSHIFT]);
            atomicAdd(&acc[g][p.y & BUKMASK], y1[p.y >> BUKSHIFT]);
            atomicAdd(&acc[g][p.z & BUKMASK], y1[p.z >> BUKSHIFT]);
            atomicAdd(&acc[g][p.w & BUKMASK], y1[p.w >> BUKSHIFT]);
        }
        if (tid < (n & 3)) {
            int p = binned[s0 + (n4 << 2) + tid];
            atomicAdd(&acc[g][p & BUKMASK], y1[p >> BUKSHIFT]);
        }
    }
    __syncthreads();
    if (tid < BUKSZ) {
        int v = (b << BUKSHIFT) + tid;
        if (v < N) {
            float a = 0.f;
            #pragma unroll
            for (int q = 0; q < 8; ++q) a += acc[q][tid];
            float d = dinv[v];
            float s = d * a + d * y1[v];
            m[v] = d * s;
        }
    }
}

// per-bucket tpos/tneg -> h2 -> per-block partial column sums
__global__ __launch_bounds__(1024) void k_acc2(const int* __restrict__ binned,
                                               const int* __restrict__ gofs,
                                               const float* __restrict__ m,
                                               const float* __restrict__ dinv,
                                               const float* __restrict__ W1,
                                               const float* __restrict__ W2,
                                               float* __restrict__ partials) {
    __shared__ float tp[8][BUKSZ], tn[8][BUKSZ];
    __shared__ float sP[16], sM[16], sAcc[16];
    const int tid = threadIdx.x;
    if (tid < 16) {
        float p = 0.f, q = 0.f;
        for (int k = 0; k < 16; ++k) {
            float w1 = W1[k];
            float w2 = W2[k * 16 + tid];
            p += fmaxf(w1, 0.f) * w2;
            q += fminf(w1, 0.f) * w2;
        }
        sP[tid] = p; sM[tid] = q; sAcc[tid] = 0.f;
    }
    for (int i = tid; i < 8 * BUKSZ; i += 1024) { (&tp[0][0])[i] = 0.f; (&tn[0][0])[i] = 0.f; }
    __syncthreads();
    const int b = blockIdx.x, g = tid >> 7;
    for (int sg = 0; sg < NGRP; ++sg) {
        const int s0 = b * CAP + sg * SUBCAP;
        const int n = gofs[(b * NGRP + sg) * GSTRIDE] - s0;
        const int n4 = n >> 2;
        const int4* b4 = (const int4*)(binned + s0);
        for (int i = tid; i < n4; i += 1024) {
            int4 p = b4[i];
            float v0 = m[p.x >> BUKSHIFT], v1 = m[p.y >> BUKSHIFT];
            float v2 = m[p.z >> BUKSHIFT], v3 = m[p.w >> BUKSHIFT];
            atomicAdd(v0 >= 0.f ? &tp[g][p.x & BUKMASK] : &tn[g][p.x & BUKMASK], v0);
            atomicAdd(v1 >= 0.f ? &tp[g][p.y & BUKMASK] : &tn[g][p.y & BUKMASK], v1);
            atomicAdd(v2 >= 0.f ? &tp[g][p.z & BUKMASK] : &tn[g][p.z & BUKMASK], v2);
            atomicAdd(v3 >= 0.f ? &tp[g][p.w & BUKMASK] : &tn[g][p.w & BUKMASK], v3);
        }
        if (tid < (n & 3)) {
            int p = binned[s0 + (n4 << 2) + tid];
            float val = m[p >> BUKSHIFT];
            atomicAdd(val >= 0.f ? &tp[g][p & BUKMASK] : &tn[g][p & BUKMASK], val);
        }
    }
    __syncthreads();
    float alpha = 0.f, beta = 0.f;
    if (tid < BUKSZ) {
        int v = (b << BUKSHIFT) + tid;
        if (v < N) {
            float a = 0.f, bb = 0.f;
            #pragma unroll
            for (int q = 0; q < 8; ++q) { a += tp[q][tid]; bb += tn[q][tid]; }
            float d = dinv[v], mv = m[v];
            alpha = d * a;
            beta  = d * bb;
            float self = d * mv;
            if (mv >= 0.f) alpha += self; else beta += self;
        }
    }
    const int lane = tid & 63;
    for (int j = 0; j < 16; ++j) {
        float h = fmaxf(alpha * sP[j] + beta * sM[j], 0.f);
        #pragma unroll
        for (int off = 32; off > 0; off >>= 1) h += __shfl_down(h, off);
        if (lane == 0 && h != 0.f) atomicAdd(&sAcc[j], h);
    }
    __syncthreads();
    if (tid < 16) partials[b * 16 + tid] = sAcc[tid];
}

// reduce partials[NBUK][16] -> mean -> out = g @ W3 + b
__global__ void k_out(const float* __restrict__ partials, const float* __restrict__ W3,
                      const float* __restrict__ b, float* __restrict__ out) {
    __shared__ float s[16][16];
    int j = threadIdx.x & 15;
    int g = threadIdx.x >> 4;
    float acc = 0.f;
    for (int blk = g; blk < NBUK; blk += 16) acc += partials[blk * 16 + j];
    s[g][j] = acc;
    __syncthreads();
    if (threadIdx.x < 16) {
        float tot = 0.f;
        #pragma unroll
        for (int gg = 0; gg < 16; ++gg) tot += s[gg][threadIdx.x];
        s[0][threadIdx.x] = tot * (1.0f / (float)N);
    }
    __syncthreads();
    if (threadIdx.x < 11) {
        float acc2 = b[threadIdx.x];
        #pragma unroll
        for (int k = 0; k < 16; ++k) acc2 += s[0][k] * W3[k * 11 + threadIdx.x];
        out[threadIdx.x] = acc2;
    }
}

extern "C" void kernel_launch(void* const* d_in, const int* in_sizes, int n_in,
                              void* d_out, int out_size, void* d_ws, size_t ws_size,
                              hipStream_t stream) {
    const float* x  = (const float*)d_in[0];
    const int*   ei = (const int*)d_in[1];   // [2*E]: rows then cols (int32)
    const float* W1 = (const float*)d_in[2];
    const float* W2 = (const float*)d_in[3];
    const float* W3 = (const float*)d_in[4];
    const float* b  = (const float*)d_in[5];
    float* out = (float*)d_out;

    int*   wsi      = (int*)d_ws;
    int*   binned   = wsi;                                      // NBUK*CAP
    float* dinv     = (float*)(wsi + (size_t)NBUK * CAP);
    float* y1       = dinv + N;
    float* m        = y1 + N;
    int*   gofs     = (int*)(m + N);                            // NBUK*NGRP*GSTRIDE
    float* partials = (float*)(gofs + NBUK * NGRP * GSTRIDE);   // NBUK*16

    const int4* rows4 = (const int4*)ei;
    const int4* cols4 = (const int4*)(ei + E);

    k_init   <<<(NBUK * NGRP + 511) / 512, 512, 0, stream>>>(gofs);
    k_scatter<<<SC_BLOCKS, SC_T, 0, stream>>>(rows4, cols4, gofs, binned);
    k_deg    <<<NBUK, 1024, 0, stream>>>(binned, gofs, x, dinv, y1);
    k_acc1   <<<NBUK, 1024, 0, stream>>>(binned, gofs, y1, dinv, m);
    k_acc2   <<<NBUK, 1024, 0, stream>>>(binned, gofs, m, dinv, W1, W2, partials);
    k_out    <<<1, 256, 0, stream>>>(partials, W3, b, out);
}